// Round 7
// baseline (31.024 us; speedup 1.0000x reference)
//
#include <hip/hip_runtime.h>
#include <math.h>

#define OUT_C   384
#define IN_C    384
#define KG      16
#define NUM_IN  16
#define NUM_OUT 16
#define PAD     17    // LDS row stride: 16 taps + circular dup w[16]=w[0]

__global__ __launch_bounds__(256) void gsub_kernel(
    const float* __restrict__ in_H,
    const float* __restrict__ out_H,
    const float* __restrict__ weight,
    float* __restrict__ out)
{
    __shared__ float s_frac[NUM_IN * NUM_OUT];
    __shared__ int   s_i0[NUM_IN * NUM_OUT];
    __shared__ float s_w[IN_C * PAD];            // all 384 ic rows

    const int t  = threadIdx.x;
    const int b  = blockIdx.x;
    const int oc = b >> 1;
    const int nh = b & 1;                        // ni half: 0 -> ni 0..7, 1 -> 8..15

    // --- issue weight loads FIRST (hide HBM latency under param math) ---
    const float4* wsrc = (const float4*)(weight + (size_t)oc * IN_C * KG);
    float4 v0 = wsrc[t];
    float4 v1 = wsrc[t + 256];
    float4 v2 = wsrc[t + 512];
    float4 v3 = wsrc[t + 768];
    float4 v4 = wsrc[t + 1024];
    float4 v5 = wsrc[t + 1280];

    // --- per-(ni,no) interpolation params (one pair per thread) ---
    {
        const int ni = t >> 4;
        const int no = t & 15;
        const float TWOPI = 6.283185307179586f;
        float c = in_H[ni] - out_H[no];          // in_H + (-out_H)
        float r = fmodf(c, TWOPI);
        if (r < 0.0f) r += TWOPI;                // jnp.mod semantics
        float pos = r * ((float)KG / TWOPI);
        float bse = floorf(pos);
        s_i0[t]   = ((int)bse) & (KG - 1);
        s_frac[t] = pos - bse;
    }

    // --- write staged weights to padded LDS; dup tap 0 at slot 16 ---
    {
        float4 vv[6] = {v0, v1, v2, v3, v4, v5};
        #pragma unroll
        for (int k = 0; k < 6; ++k) {
            int f = t + k * 256;                 // float4 index 0..1535
            int ic_l = f >> 2;
            int kq   = (f & 3) * 4;
            float* dst = &s_w[ic_l * PAD + kq];
            dst[0] = vv[k].x; dst[1] = vv[k].y; dst[2] = vv[k].z; dst[3] = vv[k].w;
            if ((f & 3) == 0) s_w[ic_l * PAD + 16] = vv[k].x;   // circular wrap
        }
    }
    __syncthreads();

    // --- main loop: wave owns 2 ni values -> 2 x 24KB fully sequential runs
    const int w   = t >> 6;                      // wave 0..3
    const int L   = t & 63;
    const int q   = L & 3;                       // no-quad
    const int icl = L >> 2;                      // ic within 16-chunk
    const int fb  = 4 * q;

    float4* ob = (float4*)out + (size_t)oc * 24576;

    #pragma unroll
    for (int p = 0; p < 2; ++p) {
        const int ni = nh * 8 + w * 2 + p;       // wave-uniform
        const float* fr = &s_frac[ni * 16 + fb];
        const int*   iz = &s_i0[ni * 16 + fb];
        float f0 = fr[0], f1 = fr[1], f2 = fr[2], f3 = fr[3];
        int   a0 = iz[0], a1 = iz[1], a2 = iz[2], a3 = iz[3];

        float4* run = ob + (size_t)ni * 1536 + L;
        #pragma unroll 4
        for (int j = 0; j < 24; ++j) {           // 24 sequential 1KB wave-stores
            const float* wrow = &s_w[(j * 16 + icl) * PAD];
            float x0 = wrow[a0], y0 = wrow[a0 + 1];
            float x1 = wrow[a1], y1 = wrow[a1 + 1];
            float x2 = wrow[a2], y2 = wrow[a2 + 1];
            float x3 = wrow[a3], y3 = wrow[a3 + 1];
            float4 vv;
            vv.x = fmaf(f0, y0 - x0, x0);
            vv.y = fmaf(f1, y1 - x1, x1);
            vv.z = fmaf(f2, y2 - x2, x2);
            vv.w = fmaf(f3, y3 - x3, x3);
            run[j * 64] = vv;
        }
    }
}

extern "C" void kernel_launch(void* const* d_in, const int* in_sizes, int n_in,
                              void* d_out, int out_size, void* d_ws, size_t ws_size,
                              hipStream_t stream) {
    const float* in_H   = (const float*)d_in[0];
    const float* out_H  = (const float*)d_in[1];
    const float* weight = (const float*)d_in[2];
    float* o = (float*)d_out;
    gsub_kernel<<<OUT_C * 2, 256, 0, stream>>>(in_H, out_H, weight, o);
}

// Round 8
// 29.784 us; speedup vs baseline: 1.0416x; 1.0416x over previous
//
#include <hip/hip_runtime.h>
#include <math.h>

#define OUT_C   384
#define IN_C    384
#define KG      16
#define NUM_IN  16
#define NUM_OUT 16
#define ICH     192   // ic rows per block (half of IN_C)
#define PAD     17    // LDS row stride: 16 taps + circular dup w[16]=w[0]

// Roofline note: output = 151 MB f32 write, weight = 9.4 MB read -> write-bound.
// Measured plateau ~29.8 us across 5 structural variants (stream count,
// persistence, sequential-run remap); steady-state ~6 TB/s after ~3 us
// launch/ramp, ~95% of the 6.3 TB/s achievable ceiling. nt stores HURT
// (34.9 us): let L2/L3 absorb the write-back stream.

__global__ __launch_bounds__(256) void gsub_kernel(
    const float* __restrict__ in_H,
    const float* __restrict__ out_H,
    const float* __restrict__ weight,
    float* __restrict__ out)
{
    __shared__ float s_frac[NUM_IN * NUM_OUT];
    __shared__ int   s_i0[NUM_IN * NUM_OUT];
    __shared__ float s_w[ICH * PAD];

    const int t = threadIdx.x;
    const int oc = blockIdx.x >> 1;
    const int h  = blockIdx.x & 1;
    const int ic_base = h * ICH;

    // --- per-(ni,no) interpolation params (one pair per thread) ---
    {
        const int ni = t >> 4;
        const int no = t & 15;
        const float TWOPI = 6.283185307179586f;
        float c = in_H[ni] - out_H[no];          // in_H + (-out_H)
        float r = fmodf(c, TWOPI);
        if (r < 0.0f) r += TWOPI;                // jnp.mod semantics
        float pos = r * ((float)KG / TWOPI);
        float b = floorf(pos);
        s_i0[t]   = ((int)b) & (KG - 1);
        s_frac[t] = pos - b;
    }

    // --- stage 192 weight rows into padded LDS; dup tap 0 at slot 16 ---
    const float4* wsrc = (const float4*)(weight + ((size_t)oc * IN_C + ic_base) * KG);
    #pragma unroll
    for (int j = 0; j < 3; ++j) {
        int f = t + j * 256;                     // float4 index 0..767
        float4 v = wsrc[f];
        int ic_l = f >> 2;
        int kq   = (f & 3) * 4;
        float* dst = &s_w[ic_l * PAD + kq];
        dst[0] = v.x; dst[1] = v.y; dst[2] = v.z; dst[3] = v.w;
        if ((f & 3) == 0) s_w[ic_l * PAD + 16] = v.x;   // circular wrap dup
    }
    __syncthreads();

    // --- main loop: thread owns (q = no-quad, lic); wave stores are 1 KB contiguous
    const int q   = t & 3;                       // no-quad 0..3
    const int lic = t >> 2;                      // 0..63

    // out as float4: index = ((oc*16+ni)*384 + ic_base + ic)*4 + q
    float4* op = (float4*)out + (size_t)oc * 24576 + (size_t)(ic_base + lic) * 4 + q;
    const int fb = 4 * q;

    for (int ni = 0; ni < 16; ++ni) {
        const float* fr = &s_frac[ni * 16 + fb];
        const int*   iz = &s_i0[ni * 16 + fb];
        float f0 = fr[0], f1 = fr[1], f2 = fr[2], f3 = fr[3];
        int   a0 = iz[0], a1 = iz[1], a2 = iz[2], a3 = iz[3];

        #pragma unroll
        for (int r = 0; r < 3; ++r) {
            const float* wrow = &s_w[(r * 64 + lic) * PAD];
            // adjacent pairs (dup at slot 16 avoids mod) -> ds_read2_b32
            float x0 = wrow[a0], y0 = wrow[a0 + 1];
            float x1 = wrow[a1], y1 = wrow[a1 + 1];
            float x2 = wrow[a2], y2 = wrow[a2 + 1];
            float x3 = wrow[a3], y3 = wrow[a3 + 1];
            float4 v;
            v.x = fmaf(f0, y0 - x0, x0);
            v.y = fmaf(f1, y1 - x1, x1);
            v.z = fmaf(f2, y2 - x2, x2);
            v.w = fmaf(f3, y3 - x3, x3);
            op[ni * 1536 + r * 256] = v;
        }
    }
}

extern "C" void kernel_launch(void* const* d_in, const int* in_sizes, int n_in,
                              void* d_out, int out_size, void* d_ws, size_t ws_size,
                              hipStream_t stream) {
    const float* in_H   = (const float*)d_in[0];
    const float* out_H  = (const float*)d_in[1];
    const float* weight = (const float*)d_in[2];
    float* o = (float*)d_out;
    gsub_kernel<<<OUT_C * 2, 256, 0, stream>>>(in_H, out_H, weight, o);
}